// Round 4
// baseline (210.816 us; speedup 1.0000x reference)
//
#include <hip/hip_runtime.h>

typedef _Float16 f16;
typedef __attribute__((ext_vector_type(4))) _Float16 f16x4;
typedef __attribute__((ext_vector_type(8))) _Float16 f16x8;
typedef __attribute__((ext_vector_type(4))) float f32x4;

#define MFMA16(a, b, c) __builtin_amdgcn_mfma_f32_16x16x32_f16((a), (b), (c), 0, 0, 0)

__device__ __forceinline__ f16x8 cvt8(float4 a, float4 b) {
    f16x8 r;
    r[0] = (f16)a.x; r[1] = (f16)a.y; r[2] = (f16)a.z; r[3] = (f16)a.w;
    r[4] = (f16)b.x; r[5] = (f16)b.y; r[6] = (f16)b.z; r[7] = (f16)b.w;
    return r;
}

// ---------------- pre-kernel: fp16 weights + fused bias constants into ws ----
__global__ void prep_kernel(const float* __restrict__ w_ih, const float* __restrict__ w_hh,
                            const float* __restrict__ b_ih, const float* __restrict__ b_hh,
                            const float* __restrict__ b_iah, const float* __restrict__ b_oah,
                            const float* __restrict__ W_in, const float* __restrict__ bias_in,
                            const float* __restrict__ W_out, const float* __restrict__ bias_out,
                            f16* __restrict__ Wc, f16* __restrict__ Whh, f16* __restrict__ Wih,
                            float* __restrict__ cstA, float* __restrict__ cstB,
                            float* __restrict__ biasc) {
    const int gid = blockIdx.x * 256 + threadIdx.x;
    const int gstride = gridDim.x * 256;
    for (int i = gid; i < 8192; i += gstride)      // Wc[j][h]: j<64 -> W_in, else W_out
        Wc[i] = (f16)(i < 4096 ? W_in[i] : W_out[i - 4096]);
    for (int i = gid; i < 12288; i += gstride) Whh[i] = (f16)w_hh[i];   // [192][64]
    for (int i = gid; i < 24576; i += gstride) Wih[i] = (f16)w_ih[i];   // [192][128]
    for (int job = gid; job < 768; job += gstride) {
        const int g = job >> 2, q = job & 3;
        float s = (q == 0) ? b_ih[g] : 0.0f;
        const float* wr = w_ih + g * 128 + q * 32;
        for (int i = 0; i < 32; ++i)
            s += wr[i] * ((q * 32 + i < 64) ? b_iah[q * 32 + i] : b_oah[q * 32 + i - 64]);
        atomicAdd(&cstA[g], s);
    }
    for (int g = gid; g < 192; g += gstride) cstB[g] = b_hh[g];
    for (int j = gid; j < 128; j += gstride) biasc[j] = (j < 64) ? bias_in[j] : bias_out[j - 64];
}

__global__ void zero_kernel(float* __restrict__ cstA) {
    if (threadIdx.x < 192) cstA[threadIdx.x] = 0.0f;
}

// ---------------- K1: inputs[b,:,half] = A_half @ hcat_half -------------------
// grid 2048 = (b, half); 256 threads = 4 waves; LDS 38.4 KB -> 4 WGs/CU.
// Phase 1: hTh[c][m] = f16(hidden[m,:]@Wc[half*64+c,:] + bias)   (transposed)
// Phase 2: 13 row-tiles, double-buffered A staging, ONE barrier per tile.
__global__ __launch_bounds__(256, 4) void k1_inputs(
    const float* __restrict__ A, const float* __restrict__ hidden,
    const f16* __restrict__ Wc, const float* __restrict__ biasc,
    f16* __restrict__ inp) {
    __shared__ __align__(16) char lds_raw[38400];
    f16* hTh = (f16*)lds_raw;             // [64][200]  25600 B
    f16* hA  = (f16*)(lds_raw + 25600);   // [2][16][200] 12800 B

    const int bid  = blockIdx.x;
    const int b    = bid >> 1;
    const int half = bid & 1;
    const float* Ab = A + (size_t)b * 80000 + (size_t)half * 40000; // [200][200]
    const float* hb = hidden + (size_t)b * 12800;                   // [200][64]
    f16* ob = inp + (size_t)b * 25600 + half * 64;                  // [200][128] slice

    const int tid = threadIdx.x;
    const int w   = tid >> 6;
    const int l   = tid & 63;
    const int l15 = l & 15;
    const int lg  = l >> 4;

    // ---- Phase 1 ----
    for (int mt = w; mt < 13; mt += 4) {
        const int m  = mt * 16 + l15;
        const int mc = m < 200 ? m : 199;
        const float* hrow = hb + mc * 64;
        float4 r0 = *(const float4*)(hrow + lg * 8);
        float4 r1 = *(const float4*)(hrow + lg * 8 + 4);
        float4 r2 = *(const float4*)(hrow + 32 + lg * 8);
        float4 r3 = *(const float4*)(hrow + 32 + lg * 8 + 4);
        f16x8 a0 = cvt8(r0, r1), a1 = cvt8(r2, r3);
        const int m0 = mt * 16 + lg * 4;
#pragma unroll
        for (int jt = 0; jt < 4; ++jt) {
            const int c0 = jt * 16 + l15;       // local col
            const int j  = half * 64 + c0;      // Wc row
            f32x4 acc = {0.f, 0.f, 0.f, 0.f};
            acc = MFMA16(a0, *(const f16x8*)(Wc + j * 64 + lg * 8), acc);
            acc = MFMA16(a1, *(const f16x8*)(Wc + j * 64 + 32 + lg * 8), acc);
            const float bc = biasc[j];
            if (m0 < 200) {
                f16x4 pk;
                pk[0] = (f16)(acc[0] + bc); pk[1] = (f16)(acc[1] + bc);
                pk[2] = (f16)(acc[2] + bc); pk[3] = (f16)(acc[3] + bc);
                *(f16x4*)(hTh + c0 * 200 + m0) = pk;
            }
        }
    }
    __syncthreads();

    // staging map: 800 float4-units (16 rows x 50 units); idx = tid + r*256
    int s_row[4], s_unit[4]; bool s_act[4];
#pragma unroll
    for (int r = 0; r < 4; ++r) {
        const int idx = tid + r * 256;
        s_act[r] = idx < 800;
        const int ic = s_act[r] ? idx : 0;
        s_row[r] = ic / 50; s_unit[r] = ic % 50;
    }

    f32x4 accC[13];
#pragma unroll
    for (int t = 0; t < 13; ++t) accC[t] = (f32x4){0.f, 0.f, 0.f, 0.f};

    // stage tile 0 -> hA[0]
    {
        float4 v[4];
#pragma unroll
        for (int r = 0; r < 4; ++r) if (s_act[r]) {
            const int n = s_row[r];
            v[r] = *(const float4*)(Ab + (size_t)n * 200 + s_unit[r] * 4);
        }
#pragma unroll
        for (int r = 0; r < 4; ++r) if (s_act[r]) {
            const int idx = tid + r * 256;
            f16x4 pk;
            pk[0] = (f16)v[r].x; pk[1] = (f16)v[r].y;
            pk[2] = (f16)v[r].z; pk[3] = (f16)v[r].w;
            *(f16x4*)(hA + idx * 4) = pk;
        }
    }
    __syncthreads();

    const f16* hTp = hTh + (w * 16 + l15) * 200;
#pragma unroll
    for (int t = 0; t < 13; ++t) {
        float4 v[4];
        if (t < 12) {                          // issue next tile's loads early
#pragma unroll
            for (int r = 0; r < 4; ++r) if (s_act[r]) {
                const int n = (t + 1) * 16 + s_row[r];
                const int nc = n < 200 ? n : 199;
                v[r] = *(const float4*)(Ab + (size_t)nc * 200 + s_unit[r] * 4);
            }
        }
        const f16* hAb = hA + (t & 1) * 3200 + l15 * 200;
#pragma unroll
        for (int k0 = 0; k0 < 224; k0 += 32) {
            const int koff = (k0 == 192) ? 192 : k0 + lg * 8;  // tail: all lanes at 192
            f16x8 a;
            if (k0 == 192 && lg != 0) {
                f16x8 z;
#pragma unroll
                for (int q = 0; q < 8; ++q) z[q] = (f16)0.0f;
                a = z;
            } else {
                a = *(const f16x8*)(hAb + koff);
            }
            f16x8 bf = *(const f16x8*)(hTp + koff);
            accC[t] = MFMA16(a, bf, accC[t]);
        }
        if (t < 12) {                          // write to the OTHER buffer
#pragma unroll
            for (int r = 0; r < 4; ++r) if (s_act[r]) {
                const int idx = tid + r * 256;
                f16x4 pk;
                pk[0] = (f16)v[r].x; pk[1] = (f16)v[r].y;
                pk[2] = (f16)v[r].z; pk[3] = (f16)v[r].w;
                *(f16x4*)(hA + ((t + 1) & 1) * 3200 + idx * 4) = pk;
            }
        }
        __syncthreads();                       // one barrier per tile
    }

    // write accC -> global inputs (f16); L2 merges the 32B segments
#pragma unroll
    for (int t = 0; t < 13; ++t) {
#pragma unroll
        for (int r = 0; r < 4; ++r) {
            const int n = t * 16 + lg * 4 + r;
            if (n < 200) ob[n * 128 + w * 16 + l15] = (f16)accC[t][r];
        }
    }
}

// ---------------- K2: gates ---------------------------------------------------
// grid 2048 = (b, row-parity); 256 threads = 4 waves; no LDS.
__global__ __launch_bounds__(256, 4) void k2_gates(
    const f16* __restrict__ inp, const float* __restrict__ hidden,
    const f16* __restrict__ Whh, const f16* __restrict__ Wih,
    const float* __restrict__ cstA, const float* __restrict__ cstB,
    float* __restrict__ out) {
    const int bid = blockIdx.x;
    const int b   = bid >> 1;
    const int p   = bid & 1;
    const f16* ib = inp + (size_t)b * 25600;      // [200][128] f16
    const float* hb = hidden + (size_t)b * 12800; // [200][64]
    float* ob = out + (size_t)b * 12800;

    const int tid = threadIdx.x;
    const int w   = tid >> 6;
    const int l   = tid & 63;
    const int l15 = l & 15;
    const int lg  = l >> 4;
    const int hcol = w * 16 + l15;

    // hoist loop-invariant weight fragments
    f16x8 Wf0[4], Wf1[4], Wf2[4];
#pragma unroll
    for (int k = 0; k < 4; ++k) {
        Wf0[k] = *(const f16x8*)(Wih + (hcol      ) * 128 + k * 32 + lg * 8);
        Wf1[k] = *(const f16x8*)(Wih + (64  + hcol) * 128 + k * 32 + lg * 8);
        Wf2[k] = *(const f16x8*)(Wih + (128 + hcol) * 128 + k * 32 + lg * 8);
    }
    f16x8 Hf0[2], Hf1[2], Hf2[2];
#pragma unroll
    for (int k = 0; k < 2; ++k) {
        Hf0[k] = *(const f16x8*)(Whh + (hcol      ) * 64 + k * 32 + lg * 8);
        Hf1[k] = *(const f16x8*)(Whh + (64  + hcol) * 64 + k * 32 + lg * 8);
        Hf2[k] = *(const f16x8*)(Whh + (128 + hcol) * 64 + k * 32 + lg * 8);
    }
    const float cAr = cstA[hcol], cAi = cstA[64 + hcol], cAn = cstA[128 + hcol];
    const float cBr = cstB[hcol], cBi = cstB[64 + hcol], cBn = cstB[128 + hcol];

    for (int t = p; t < 13; t += 2) {
        const int n  = t * 16 + l15;
        const int nc = n < 200 ? n : 199;
        f32x4 gir = {0.f,0.f,0.f,0.f}, gii = {0.f,0.f,0.f,0.f}, gin = {0.f,0.f,0.f,0.f};
        f32x4 ghr = {0.f,0.f,0.f,0.f}, ghi = {0.f,0.f,0.f,0.f}, ghn = {0.f,0.f,0.f,0.f};
#pragma unroll
        for (int k = 0; k < 4; ++k) {          // gi: K = 128, inp row-gather (L3-hot)
            f16x8 a = *(const f16x8*)(ib + nc * 128 + k * 32 + lg * 8);
            gir = MFMA16(a, Wf0[k], gir);
            gii = MFMA16(a, Wf1[k], gii);
            gin = MFMA16(a, Wf2[k], gin);
        }
#pragma unroll
        for (int k = 0; k < 2; ++k) {          // gh: K = 64
            const int h = k * 32 + lg * 8;
            float4 r0 = *(const float4*)(hb + nc * 64 + h);
            float4 r1 = *(const float4*)(hb + nc * 64 + h + 4);
            f16x8 a = cvt8(r0, r1);
            ghr = MFMA16(a, Hf0[k], ghr);
            ghi = MFMA16(a, Hf1[k], ghi);
            ghn = MFMA16(a, Hf2[k], ghn);
        }
#pragma unroll
        for (int r = 0; r < 4; ++r) {
            const int row = t * 16 + lg * 4 + r;
            if (row < 200) {
                const float hv = hb[row * 64 + hcol];
                const float xr = gir[r] + ghr[r] + cAr + cBr;
                const float xi = gii[r] + ghi[r] + cAi + cBi;
                const float rg = 1.0f / (1.0f + __expf(-xr));
                const float ig = 1.0f / (1.0f + __expf(-xi));
                const float xn = gin[r] + cAn + rg * (ghn[r] + cBn);
                const float e2 = __expf(2.0f * xn);
                const float ng = 1.0f - 2.0f / (e2 + 1.0f);
                ob[row * 64 + hcol] = hv + ig * (ng - hv);
            }
        }
    }
}

extern "C" void kernel_launch(void* const* d_in, const int* in_sizes, int n_in,
                              void* d_out, int out_size, void* d_ws, size_t ws_size,
                              hipStream_t stream) {
    const float* A        = (const float*)d_in[0];
    const float* hidden   = (const float*)d_in[1];
    const float* w_ih     = (const float*)d_in[2];
    const float* w_hh     = (const float*)d_in[3];
    const float* b_ih     = (const float*)d_in[4];
    const float* b_hh     = (const float*)d_in[5];
    const float* b_iah    = (const float*)d_in[6];
    const float* b_oah    = (const float*)d_in[7];
    const float* W_in     = (const float*)d_in[8];
    const float* bias_in  = (const float*)d_in[9];
    const float* W_out    = (const float*)d_in[10];
    const float* bias_out = (const float*)d_in[11];
    float* out = (float*)d_out;

    char* wsb = (char*)d_ws;
    f16* Wc      = (f16*)wsb;            // 8192 f16
    f16* Whh     = Wc + 8192;            // 12288 f16
    f16* Wih     = Whh + 12288;          // 24576 f16
    float* cstA  = (float*)(wsb + 90112);
    float* cstB  = cstA + 192;
    float* biasc = cstB + 192;
    f16* inp     = (f16*)(wsb + 92160);  // 1024*200*128 f16 = 52.4 MB

    zero_kernel<<<dim3(1), dim3(256), 0, stream>>>(cstA);
    prep_kernel<<<dim3(64), dim3(256), 0, stream>>>(
        w_ih, w_hh, b_ih, b_hh, b_iah, b_oah, W_in, bias_in, W_out, bias_out,
        Wc, Whh, Wih, cstA, cstB, biasc);
    k1_inputs<<<dim3(2048), dim3(256), 0, stream>>>(A, hidden, Wc, biasc, inp);
    k2_gates<<<dim3(2048), dim3(256), 0, stream>>>(inp, hidden, Whh, Wih, cstA, cstB, out);
}